// Round 7
// baseline (181.826 us; speedup 1.0000x reference)
//
#include <hip/hip_runtime.h>
#include <stdint.h>

// RGCNConv: out = sum_r ((A * [edge==r]) @ x) @ W_r + bias
// N=4096, IN=OUT=256, R=8.
//   k_init : out[i][o] = bias[o]
//   k_y    : yt2[(j*256+o)*8+r] = (x @ W_r)[j][o]  (bf16 granules, ws 16 MB)
//   k_main : expanded GEMM out[i][o] += sum_j A[i][j]*yt2[j][o][e[i][j]]
//            Block 256i x 256o, 8 waves (2x4), wave tile 128x64, 32x32x16.
//            GRANULE-MAJOR LDS [plane j][row]x16B: all frag reads/writes
//            contiguous (no bank conflicts); B DMA source contiguous.
//            Counted vmcnt(2) + one s_barrier per 8-j step; staggered
//            atomic epilogue across ksplit.

#define NN 4096

typedef __attribute__((ext_vector_type(8)))  short s16x8;   // 8 bf16 MFMA frag
typedef __attribute__((ext_vector_type(16))) float f32x16;  // 32x32 C/D
typedef __attribute__((ext_vector_type(4)))  float fx4;
typedef __attribute__((ext_vector_type(4)))  int   ix4;
typedef __attribute__((ext_vector_type(4)))  unsigned int ux4;

union uq { ux4 u; s16x8 s; };

__device__ __forceinline__ unsigned short f2bf(float f) {
  union { float f; unsigned int u; } v; v.f = f;
  unsigned int r = v.u + 0x7fffu + ((v.u >> 16) & 1u);  // RNE
  return (unsigned short)(r >> 16);
}

__device__ __forceinline__ void gld16(const void* g, void* l) {
  __builtin_amdgcn_global_load_lds(
      (const __attribute__((address_space(1))) unsigned int*)(uintptr_t)g,
      (__attribute__((address_space(3))) unsigned int*)(uintptr_t)l, 16, 0, 0);
}

// ---------------- init: out = bias ----------------
__global__ void k_init(const float* __restrict__ bias, float* __restrict__ out) {
  int idx = blockIdx.x * 256 + threadIdx.x;
  out[idx] = bias[idx & 255];
}

// ---------------- yt2[(j*256+o)*8+r] = sum_k x[j][k] * W[r][k][o] ----------------
__global__ __launch_bounds__(256, 2) void k_y(const float* __restrict__ x,
                                              const float* __restrict__ W,
                                              unsigned short* __restrict__ yt) {
  __shared__ unsigned short Wl[128 * 256];  // 64 KB
  const int t  = threadIdx.x;
  const int j0 = blockIdx.x * 128;
  const int o0 = blockIdx.y * 16;

  {
    const int r = t >> 5, kc = t & 31;
#pragma unroll
    for (int u = 0; u < 8; ++u) {
      const int k = kc * 8 + u;
      const fx4* wp = (const fx4*)(W + ((size_t)r * 256 + k) * 256 + o0);
      fx4 w[4] = { wp[0], wp[1], wp[2], wp[3] };
#pragma unroll
      for (int i = 0; i < 16; ++i) {
        const int row = i * 8 + r;               // n'
        const int gs  = (k >> 3) ^ (row & 7);    // swizzled 16B granule
        Wl[row * 256 + gs * 8 + (k & 7)] = f2bf(w[i >> 2][i & 3]);
      }
    }
  }
  __syncthreads();

  const int lane = t & 63, wid = t >> 6;
  const int l15 = lane & 15, lh = lane >> 4;
  const int npb = wid * 32;

  fx4 acc[8][2];
#pragma unroll
  for (int m = 0; m < 8; ++m)
#pragma unroll
    for (int n = 0; n < 2; ++n) acc[m][n] = 0.f;

  unsigned int qb[2];
#pragma unroll
  for (int n = 0; n < 2; ++n) {
    int row = npb + n * 16 + l15;
    qb[n] = (unsigned)(row * 512 + 16 * (lh ^ (row & 3))) ^ (64u * ((row >> 2) & 1));
  }
  const char* WlB = (const char*)Wl;
  const float* xb = x + (size_t)(j0 + l15) * 256 + lh * 8;

#pragma unroll
  for (int ks = 0; ks < 8; ++ks) {
    s16x8 a[8];
#pragma unroll
    for (int m = 0; m < 8; ++m) {
      const fx4* xp = (const fx4*)(xb + (size_t)m * 16 * 256 + ks * 32);
      fx4 x0 = xp[0], x1 = xp[1];
      s16x8 av;
#pragma unroll
      for (int i = 0; i < 4; ++i) av[i] = (short)f2bf(x0[i]);
#pragma unroll
      for (int i = 0; i < 4; ++i) av[4 + i] = (short)f2bf(x1[i]);
      a[m] = av;
    }
#pragma unroll
    for (int n = 0; n < 2; ++n) {
      s16x8 b = *(const s16x8*)(WlB + (qb[n] ^ (unsigned)(ks * 64)));
#pragma unroll
      for (int m = 0; m < 8; ++m)
        acc[m][n] = __builtin_amdgcn_mfma_f32_16x16x32_bf16(a[m], b, acc[m][n], 0, 0, 0);
    }
  }

  // store: yt2 granule (j*256 + o), slot r
#pragma unroll
  for (int m = 0; m < 8; ++m)
#pragma unroll
    for (int n = 0; n < 2; ++n)
#pragma unroll
      for (int q = 0; q < 4; ++q) {
        int jl = m * 16 + lh * 4 + q;
        int np = npb + n * 16 + l15;
        int o  = o0 + (np >> 3);
        yt[((size_t)(j0 + jl) * 256 + o) * 8 + (np & 7)] = f2bf(acc[m][n][q]);
      }
}

// ---------------- main expanded GEMM ----------------
// grid (16 itiles, 16 ksplit) = 256 blocks (1/CU). Block 256i x 256o,
// 512 thr / 8 waves, wave-grid 2(i) x 4(o), wave tile 128x64 (m4 x n2).
// Step = 8 j (K_eff 64, 4 k-slices of 16). Granule plane = j_local (0..7).
// LDS 128 KB: A one-hot [2 buf][8 plane][256 i]x16B @0,
//             B yt2    [2 buf][8 plane][256 o]x16B @64K.
// Frag (m|n, ks): plane 2ks+lh1, rows consecutive in l31 -> conflict-free.
// Per iter: wait vmcnt(2) lgkmcnt(0); s_barrier; DMA B(s+1) (contiguous src);
// fence; load AE(s+2); build one-hot A(s+1); compute s.
__global__ __launch_bounds__(512, 2) void k_main(const float* __restrict__ A,
                                                 const int*   __restrict__ et,
                                                 const unsigned short* __restrict__ yt,
                                                 float* __restrict__ out) {
  __shared__ ux4 smem[8192];  // 131072 B
  char* smc = (char*)smem;
  const int t = threadIdx.x, lane = t & 63, w = t >> 6;
  const int l31 = lane & 31, lh1 = lane >> 5;
  const int wm = w >> 2, wn = w & 3;
  const int i0 = blockIdx.x * 256;
  const int kz = blockIdx.y;
  const int jb = kz * 256;

  // builders: thread -> (row bi, j-quad bq)
  const int bi = t >> 1, bq = t & 1;
  const fx4* pA = (const fx4*)(A  + (size_t)(i0 + bi) * NN + jb + bq * 4);
  const ix4* pE = (const ix4*)(et + (size_t)(i0 + bi) * NN + jb + bq * 4);
  unsigned awr[4];
#pragma unroll
  for (int k = 0; k < 4; ++k)
    awr[k] = (unsigned)((bq * 4 + k) * 4096 + bi * 16);  // plane-major

  // B DMA: wave w stages plane w; source = 64 consecutive yt2 granules
  const ux4* ytg = (const ux4*)yt;  // granule view [(j*256+o)]
  const ux4* sBsrc[4];
#pragma unroll
  for (int u = 0; u < 4; ++u)
    sBsrc[u] = ytg + ((size_t)(jb + w) * 256 + u * 64 + lane);

  // frag read bases (plane-major): + buf + ks*8192
  unsigned QA[4], QB[2];
#pragma unroll
  for (int m = 0; m < 4; ++m)
    QA[m] = (unsigned)(lh1 * 4096 + (wm * 128 + m * 32 + l31) * 16);
#pragma unroll
  for (int n = 0; n < 2; ++n)
    QB[n] = (unsigned)(65536 + lh1 * 4096 + (wn * 64 + n * 32 + l31) * 16);

  f32x16 acc[4][2];
#pragma unroll
  for (int m = 0; m < 4; ++m)
#pragma unroll
    for (int n = 0; n < 2; ++n) acc[m][n] = 0.f;

  // prologue: DMA B(0); then AE(0), AE(1); build A(0) into buf0
#pragma unroll
  for (int u = 0; u < 4; ++u)
    gld16(sBsrc[u], smc + 65536 + w * 4096 + u * 1024);
  asm volatile("" ::: "memory");  // keep AE loads after the DMAs
  fx4 a0 = pA[0]; ix4 e0 = pE[0];
  fx4 aN = pA[2]; ix4 eN = pE[2];
#pragma unroll
  for (int k = 0; k < 4; ++k) {
    unsigned long long sh = ((unsigned long long)f2bf(a0[k])) << ((e0[k] & 3) * 16);
    unsigned lo = (unsigned)sh, hi = (unsigned)(sh >> 32);
    bool c = e0[k] < 4;
    ux4 q; q.x = c ? lo : 0u; q.y = c ? hi : 0u; q.z = c ? 0u : lo; q.w = c ? 0u : hi;
    *(ux4*)(smc + awr[k]) = q;
  }

  for (int s = 0; s < 32; ++s) {
    asm volatile("s_waitcnt vmcnt(2) lgkmcnt(0)" ::: "memory");  // B(s)+builds done
    __builtin_amdgcn_s_barrier();
    const int s1 = (s + 1 < 32) ? s + 1 : 31;
    const int s2 = (s + 2 < 32) ? s + 2 : 31;
    const unsigned nb = (unsigned)(((s + 1) & 1) * 32768);
    // DMA B(s+1) -> buf (s+1)&1 (freed: consumed in iter s-1, barrier passed)
#pragma unroll
    for (int u = 0; u < 4; ++u)
      gld16(sBsrc[u] + (size_t)s1 * 2048, smc + 65536 + nb + w * 4096 + u * 1024);
    asm volatile("" ::: "memory");  // AE loads stay AFTER DMAs (vmcnt order)
    fx4 a2 = pA[2 * s2]; ix4 e2 = pE[2 * s2];
    // build one-hot A(s+1) -> buf (s+1)&1
#pragma unroll
    for (int k = 0; k < 4; ++k) {
      unsigned long long sh = ((unsigned long long)f2bf(aN[k])) << ((eN[k] & 3) * 16);
      unsigned lo = (unsigned)sh, hi = (unsigned)(sh >> 32);
      bool c = eN[k] < 4;
      ux4 q; q.x = c ? lo : 0u; q.y = c ? hi : 0u; q.z = c ? 0u : lo; q.w = c ? 0u : hi;
      *(ux4*)(smc + nb + awr[k]) = q;
    }
    // compute step s from buf s&1
    const unsigned cb = (unsigned)((s & 1) * 32768);
#pragma unroll
    for (int ks = 0; ks < 4; ++ks) {
      uq a[4], b[2];
#pragma unroll
      for (int m = 0; m < 4; ++m)
        a[m].u = *(const ux4*)(smc + cb + QA[m] + (unsigned)(ks * 8192));
#pragma unroll
      for (int n = 0; n < 2; ++n)
        b[n].u = *(const ux4*)(smc + cb + QB[n] + (unsigned)(ks * 8192));
#pragma unroll
      for (int m = 0; m < 4; ++m)
#pragma unroll
        for (int n = 0; n < 2; ++n)
          acc[m][n] = __builtin_amdgcn_mfma_f32_32x32x16_bf16(a[m].s, b[n].s, acc[m][n], 0, 0, 0);
    }
    aN = a2; eN = e2;
  }
  asm volatile("s_waitcnt vmcnt(0)" ::: "memory");  // drain DMA before exit

  // epilogue: staggered K-split partial accumulate.
  // 32x32 C layout: col = l31, row = (q&3) + 8*(q>>2) + 4*lh1
#pragma unroll
  for (int mm = 0; mm < 4; ++mm) {
    const int m = (mm + kz) & 3;
#pragma unroll
    for (int n = 0; n < 2; ++n)
#pragma unroll
      for (int qq = 0; qq < 16; ++qq) {
        const int q = (qq + ((kz >> 2) << 2)) & 15;
        int gi = i0 + wm * 128 + m * 32 + (q & 3) + 8 * (q >> 2) + 4 * lh1;
        int go = wn * 64 + n * 32 + l31;
        atomicAdd(out + (size_t)gi * 256 + go, acc[m][n][q]);
      }
  }
}

extern "C" void kernel_launch(void* const* d_in, const int* in_sizes, int n_in,
                              void* d_out, int out_size, void* d_ws, size_t ws_size,
                              hipStream_t stream) {
  const float* x    = (const float*)d_in[0];
  const float* A    = (const float*)d_in[1];
  const int*   et   = (const int*)d_in[2];
  const float* W    = (const float*)d_in[3];
  const float* bias = (const float*)d_in[4];
  float* out = (float*)d_out;
  unsigned short* yt = (unsigned short*)d_ws;  // 16 MB granule-major yt2

  k_init<<<dim3(4096), dim3(256), 0, stream>>>(bias, out);
  k_y   <<<dim3(32, 16), dim3(256), 0, stream>>>(x, W, yt);
  k_main<<<dim3(16, 16), dim3(512), 0, stream>>>(A, et, yt, out);
}

// Round 8
// 127.880 us; speedup vs baseline: 1.4218x; 1.4218x over previous
//
#include <hip/hip_runtime.h>
#include <stdint.h>

// RGCNConv: out = sum_r ((A * [edge==r]) @ x) @ W_r + bias
// N=4096, IN=OUT=256, R=8.
//   k_y    : yt2[(j*256+o)*8+r] = (x @ W_r)[j][o]  (bf16 granules, ws[0,16MB))
//   k_main : expanded GEMM out[i][o] += sum_j A[i][j]*yt2[j][o][e[i][j]]
//            Block 256i x 256o, 8 waves (4i x 2o), wave tile 64x128 (m2 n4),
//            32x32x16 MFMA. ALL streams (rawA, rawE, B) via global_load_lds
//            into 3-deep circular stages; vmcnt(6) counted wait (never 0 in
//            loop); NO register global loads in the loop (the r4-r7 bug:
//            they forced a vmcnt(0) drain each step). One-hot A frags built
//            in regs from LDS readback.
//   epilogue: partials to ws + k_red (no atomics) if ws_size >= 80MB,
//             else bias-init + atomicAdd fallback.

#define NN 4096

typedef __attribute__((ext_vector_type(8)))  short s16x8;   // 8 bf16 MFMA frag
typedef __attribute__((ext_vector_type(16))) float f32x16;  // 32x32 C/D
typedef __attribute__((ext_vector_type(4)))  float fx4;
typedef __attribute__((ext_vector_type(4)))  int   ix4;
typedef __attribute__((ext_vector_type(4)))  unsigned int ux4;

union uq { ux4 u; s16x8 s; };

__device__ __forceinline__ unsigned short f2bf(float f) {
  union { float f; unsigned int u; } v; v.f = f;
  unsigned int r = v.u + 0x7fffu + ((v.u >> 16) & 1u);  // RNE
  return (unsigned short)(r >> 16);
}

__device__ __forceinline__ void gld16(const void* g, void* l) {
  __builtin_amdgcn_global_load_lds(
      (const __attribute__((address_space(1))) unsigned int*)(uintptr_t)g,
      (__attribute__((address_space(3))) unsigned int*)(uintptr_t)l, 16, 0, 0);
}

// ---------------- init: out = bias (atomic fallback path only) -------------
__global__ void k_init(const float* __restrict__ bias, float* __restrict__ out) {
  int idx = blockIdx.x * 256 + threadIdx.x;
  out[idx] = bias[idx & 255];
}

// ---------------- yt2[(j*256+o)*8+r] = sum_k x[j][k] * W[r][k][o] ----------
__global__ __launch_bounds__(256, 2) void k_y(const float* __restrict__ x,
                                              const float* __restrict__ W,
                                              unsigned short* __restrict__ yt) {
  __shared__ unsigned short Wl[128 * 256];  // 64 KB
  const int t  = threadIdx.x;
  const int j0 = blockIdx.x * 128;
  const int o0 = blockIdx.y * 16;

  {
    const int r = t >> 5, kc = t & 31;
#pragma unroll
    for (int u = 0; u < 8; ++u) {
      const int k = kc * 8 + u;
      const fx4* wp = (const fx4*)(W + ((size_t)r * 256 + k) * 256 + o0);
      fx4 w[4] = { wp[0], wp[1], wp[2], wp[3] };
#pragma unroll
      for (int i = 0; i < 16; ++i) {
        const int row = i * 8 + r;               // n'
        const int gs  = (k >> 3) ^ (row & 7);    // swizzled 16B granule
        Wl[row * 256 + gs * 8 + (k & 7)] = f2bf(w[i >> 2][i & 3]);
      }
    }
  }
  __syncthreads();

  const int lane = t & 63, wid = t >> 6;
  const int l15 = lane & 15, lh = lane >> 4;
  const int npb = wid * 32;

  fx4 acc[8][2];
#pragma unroll
  for (int m = 0; m < 8; ++m)
#pragma unroll
    for (int n = 0; n < 2; ++n) acc[m][n] = 0.f;

  unsigned int qb[2];
#pragma unroll
  for (int n = 0; n < 2; ++n) {
    int row = npb + n * 16 + l15;
    qb[n] = (unsigned)(row * 512 + 16 * (lh ^ (row & 3))) ^ (64u * ((row >> 2) & 1));
  }
  const char* WlB = (const char*)Wl;
  const float* xb = x + (size_t)(j0 + l15) * 256 + lh * 8;

#pragma unroll
  for (int ks = 0; ks < 8; ++ks) {
    s16x8 a[8];
#pragma unroll
    for (int m = 0; m < 8; ++m) {
      const fx4* xp = (const fx4*)(xb + (size_t)m * 16 * 256 + ks * 32);
      fx4 x0 = xp[0], x1 = xp[1];
      s16x8 av;
#pragma unroll
      for (int i = 0; i < 4; ++i) av[i] = (short)f2bf(x0[i]);
#pragma unroll
      for (int i = 0; i < 4; ++i) av[4 + i] = (short)f2bf(x1[i]);
      a[m] = av;
    }
#pragma unroll
    for (int n = 0; n < 2; ++n) {
      s16x8 b = *(const s16x8*)(WlB + (qb[n] ^ (unsigned)(ks * 64)));
#pragma unroll
      for (int m = 0; m < 8; ++m)
        acc[m][n] = __builtin_amdgcn_mfma_f32_16x16x32_bf16(a[m], b, acc[m][n], 0, 0, 0);
    }
  }

#pragma unroll
  for (int m = 0; m < 8; ++m)
#pragma unroll
    for (int n = 0; n < 2; ++n)
#pragma unroll
      for (int q = 0; q < 4; ++q) {
        int jl = m * 16 + lh * 4 + q;
        int np = npb + n * 16 + l15;
        int o  = o0 + (np >> 3);
        yt[((size_t)(j0 + jl) * 256 + o) * 8 + (np & 7)] = f2bf(acc[m][n][q]);
      }
}

// ---------------- main expanded GEMM ----------------
// grid (16 itiles, 16 ksplit) = 256 blocks (1/CU). Block 256i x 256o.
// 512 thr / 8 waves, wave-grid 4(i) x 2(o): wave tile 64i x 128o = m2 x n4
// 32x32x16 reps. Step = 8 j; j-local(ks,lh1) = 4*lh1 + ks.
// LDS 144 KB: 3 stages x 48 KB: rawA [256 i][2 q]x16B @0 (quad XOR-swz),
//   rawE same @8K, B planes [8][256 o]x16B @16K (linear; contiguous source).
// Per iter/thread: 6 gld16 (1 A, 1 E, 4 B). Top: vmcnt(6) (stage s done,
// stage s+1 in flight), s_barrier, issue stage s+2, compute s.
// A one-hot frags built in registers from rawA/rawE LDS readback.
__global__ __launch_bounds__(512, 2) void k_main(const float* __restrict__ A,
                                                 const int*   __restrict__ et,
                                                 const unsigned short* __restrict__ yt,
                                                 float* __restrict__ dst,
                                                 int usePart) {
  __shared__ ux4 smem[9216];  // 147456 B = 3 x 48 KB
  char* smc = (char*)smem;
  const int t = threadIdx.x, lane = t & 63, w = t >> 6;
  const int l31 = lane & 31, lh1 = lane >> 5;
  const int wm = w & 3, wn = w >> 2;
  const int i0 = blockIdx.x * 256;
  const int kz = blockIdx.y;
  const int jb = kz * 256;

  // raw A/E DMA source: thread t -> dest (row di = t>>1, phys quad dq = t&1);
  // phys quad dq holds logical quad dq ^ ((di>>2)&1)  (4-way-max readback)
  const int di = t >> 1, dq = t & 1;
  const int lq = dq ^ ((di >> 2) & 1);
  const float* srcA = A  + (size_t)(i0 + di) * NN + jb + lq * 4;
  const int*   srcE = et + (size_t)(i0 + di) * NN + jb + lq * 4;
  // B DMA source: fully linear copy (granule k of stage = yt2[(jb+s*8)*256 + k])
  const ux4* ytg = (const ux4*)yt;
  const size_t bsrc0 = (size_t)jb * 256 + w * 256 + lane;

#define ISSUE(sq, pbase) do {                                             \
    gld16(srcA + (size_t)(sq) * 8, smc + (pbase) + w * 1024);             \
    gld16(srcE + (size_t)(sq) * 8, smc + (pbase) + 8192 + w * 1024);      \
    _Pragma("unroll")                                                     \
    for (int u = 0; u < 4; ++u)                                           \
      gld16(ytg + bsrc0 + (size_t)(sq) * 2048 + u * 64,                   \
            smc + (pbase) + 16384 + w * 4096 + u * 1024);                 \
  } while (0)

  // readback bases
  unsigned rA[2];
#pragma unroll
  for (int m = 0; m < 2; ++m) {
    int il = wm * 64 + m * 32 + l31;
    rA[m] = (unsigned)(il * 32 + ((lh1 ^ ((il >> 2) & 1)) << 4));
  }
  unsigned rB[4];
#pragma unroll
  for (int n = 0; n < 4; ++n)
    rB[n] = (unsigned)(16384 + lh1 * 16384 + (wn * 128 + n * 32 + l31) * 16);

  f32x16 acc[2][4];
#pragma unroll
  for (int m = 0; m < 2; ++m)
#pragma unroll
    for (int n = 0; n < 4; ++n) acc[m][n] = 0.f;

  // prologue: 2 stages in flight
  ISSUE(0, 0);
  ISSUE(1, 49152);

  int pb0 = 0, pb1 = 49152, pb2 = 98304;
  for (int s = 0; s < 32; ++s) {
    asm volatile("s_waitcnt vmcnt(6)" ::: "memory");  // stage s landed (own)
    __builtin_amdgcn_s_barrier();                     // everyone's stage s visible
    {
      const int sq = (s + 2 < 32) ? s + 2 : 31;       // dup-issue tail: harmless
      ISSUE(sq, pb2);
    }
    fx4 av[2]; ix4 ev[2];
#pragma unroll
    for (int m = 0; m < 2; ++m) {
      av[m] = *(const fx4*)(smc + pb0 + rA[m]);
      ev[m] = *(const ix4*)(smc + pb0 + 8192 + rA[m]);
    }
#pragma unroll
    for (int ks = 0; ks < 4; ++ks) {
      uq a[2];
#pragma unroll
      for (int m = 0; m < 2; ++m) {
        float avv = av[m][ks]; int evv = ev[m][ks];
        unsigned long long sh = ((unsigned long long)f2bf(avv)) << ((evv & 3) * 16);
        unsigned lo = (unsigned)sh, hi = (unsigned)(sh >> 32);
        bool c = evv < 4;
        ux4 q; q.x = c ? lo : 0u; q.y = c ? hi : 0u; q.z = c ? 0u : lo; q.w = c ? 0u : hi;
        a[m].u = q;
      }
#pragma unroll
      for (int n = 0; n < 4; ++n) {
        uq b; b.u = *(const ux4*)(smc + pb0 + rB[n] + (unsigned)(ks * 4096));
#pragma unroll
        for (int m = 0; m < 2; ++m)
          acc[m][n] = __builtin_amdgcn_mfma_f32_32x32x16_bf16(a[m].s, b.s, acc[m][n], 0, 0, 0);
      }
    }
    int tmp = pb0; pb0 = pb1; pb1 = pb2; pb2 = tmp;
  }
  asm volatile("s_waitcnt vmcnt(0)" ::: "memory");  // drain DMA before exit

  // epilogue. 32x32 C layout: col = l31, row = (q&3) + 8*(q>>2) + 4*lh1
  if (usePart) {
    float* pp = dst + ((size_t)kz << 20);
#pragma unroll
    for (int m = 0; m < 2; ++m)
#pragma unroll
      for (int n = 0; n < 4; ++n)
#pragma unroll
        for (int q = 0; q < 16; ++q) {
          int gi = i0 + wm * 64 + m * 32 + (q & 3) + 8 * (q >> 2) + 4 * lh1;
          int go = wn * 128 + n * 32 + l31;
          pp[(size_t)gi * 256 + go] = acc[m][n][q];
        }
  } else {
#pragma unroll
    for (int m = 0; m < 2; ++m)
#pragma unroll
      for (int n = 0; n < 4; ++n)
#pragma unroll
        for (int q = 0; q < 16; ++q) {
          int gi = i0 + wm * 64 + m * 32 + (q & 3) + 8 * (q >> 2) + 4 * lh1;
          int go = wn * 128 + n * 32 + l31;
          atomicAdd(dst + (size_t)gi * 256 + go, acc[m][n][q]);
        }
  }
#undef ISSUE
}

// ---------------- reduce 16 partials + bias -> out ----------------
__global__ __launch_bounds__(256) void k_red(const float* __restrict__ part,
                                             const float* __restrict__ bias,
                                             float* __restrict__ out) {
  int idx = blockIdx.x * 256 + threadIdx.x;           // fx4 index, 262144 total
  fx4 s = *(const fx4*)(bias + ((idx << 2) & 255));
  const fx4* p4 = (const fx4*)part;
#pragma unroll
  for (int k = 0; k < 16; ++k) s += p4[((size_t)k << 18) + idx];
  ((fx4*)out)[idx] = s;
}

extern "C" void kernel_launch(void* const* d_in, const int* in_sizes, int n_in,
                              void* d_out, int out_size, void* d_ws, size_t ws_size,
                              hipStream_t stream) {
  const float* x    = (const float*)d_in[0];
  const float* A    = (const float*)d_in[1];
  const int*   et   = (const int*)d_in[2];
  const float* W    = (const float*)d_in[3];
  const float* bias = (const float*)d_in[4];
  float* out = (float*)d_out;
  unsigned short* yt = (unsigned short*)d_ws;  // 16 MB granule-major yt2

  const size_t YT = (size_t)16 << 20;
  const bool usePart = ws_size >= YT + ((size_t)64 << 20);

  k_y<<<dim3(32, 16), dim3(256), 0, stream>>>(x, W, yt);
  if (usePart) {
    float* pbuf = (float*)((char*)d_ws + YT);  // 16 x 4MB f32 partials
    k_main<<<dim3(16, 16), dim3(512), 0, stream>>>(A, et, yt, pbuf, 1);
    k_red<<<dim3(1024), dim3(256), 0, stream>>>(pbuf, bias, out);
  } else {
    k_init<<<dim3(4096), dim3(256), 0, stream>>>(bias, out);
    k_main<<<dim3(16, 16), dim3(512), 0, stream>>>(A, et, yt, out, 0);
  }
}